// Round 1
// baseline (494.217 us; speedup 1.0000x reference)
//
#include <hip/hip_runtime.h>

// MaskedNormalize: x (16, 4, 1024, 1024) fp32. valid = x != 0.
// Per-sample (axis 1,2,3) masked mean/var (unbiased), out = valid ? (x-mean)/(sqrt(var)+eps) : 0.
// Key: masked-out entries are exactly 0 -> contribute nothing to S1/S2; m2 == 0 analytically.

#define EPS 1e-5

constexpr int    B               = 16;
constexpr int    VEC_PER_SAMPLE  = 1048576;              // 4194304 floats / 4 per sample
constexpr int    RED_BLOCKS_PS   = 128;                  // reduction blocks per sample
constexpr int    RED_THREADS     = 256;
constexpr int    NORM_BLOCKS_PS  = 4096;                 // 4096 * 256 threads * 1 float4 = sample
constexpr int    NORM_THREADS    = 256;

__device__ inline void wave_reduce(double& s1, double& s2, int& c) {
    #pragma unroll
    for (int off = 32; off > 0; off >>= 1) {
        s1 += __shfl_down(s1, off);
        s2 += __shfl_down(s2, off);
        c  += __shfl_down(c,  off);
    }
}

// Pass 1: per-sample sum, sumsq, valid-count into ws[sample*3 + {0,1,2}] (doubles).
__global__ __launch_bounds__(RED_THREADS)
void masked_stats_kernel(const float4* __restrict__ x, double* __restrict__ ws) {
    const int sample = blockIdx.x / RED_BLOCKS_PS;
    const int blk    = blockIdx.x % RED_BLOCKS_PS;
    const float4* xs = x + (size_t)sample * VEC_PER_SAMPLE;

    double s1 = 0.0, s2 = 0.0;
    int cnt = 0;

    const int stride = RED_BLOCKS_PS * RED_THREADS;   // 32768 threads per sample
    for (int i = blk * RED_THREADS + threadIdx.x; i < VEC_PER_SAMPLE; i += stride) {
        float4 v = xs[i];
        // invalid entries are exactly 0 -> add unconditionally (0 contributes 0)
        s1 += (double)v.x + (double)v.y + (double)v.z + (double)v.w;
        s2 += (double)v.x * v.x + (double)v.y * v.y
            + (double)v.z * v.z + (double)v.w * v.w;
        cnt += (v.x != 0.0f) + (v.y != 0.0f) + (v.z != 0.0f) + (v.w != 0.0f);
    }

    wave_reduce(s1, s2, cnt);

    __shared__ double L1[4], L2[4];
    __shared__ int    LC[4];
    const int wave = threadIdx.x >> 6;
    const int lane = threadIdx.x & 63;
    if (lane == 0) { L1[wave] = s1; L2[wave] = s2; LC[wave] = cnt; }
    __syncthreads();
    if (threadIdx.x == 0) {
        double t1 = 0.0, t2 = 0.0; int tc = 0;
        #pragma unroll
        for (int w = 0; w < 4; ++w) { t1 += L1[w]; t2 += L2[w]; tc += LC[w]; }
        atomicAdd(&ws[sample * 3 + 0], t1);
        atomicAdd(&ws[sample * 3 + 1], t2);
        atomicAdd(&ws[sample * 3 + 2], (double)tc);
    }
}

// Pass 2: out = valid ? (x - mean) * inv : 0
__global__ __launch_bounds__(NORM_THREADS)
void masked_norm_kernel(const float4* __restrict__ x, float4* __restrict__ out,
                        const double* __restrict__ ws) {
    const int sample = blockIdx.x >> 12;              // / NORM_BLOCKS_PS

    const double sum   = ws[sample * 3 + 0];
    const double sumsq = ws[sample * 3 + 1];
    const double n     = ws[sample * 3 + 2];
    const double mean  = sum / n;
    const double var   = (sumsq - sum * sum / n) / (n - 1.0);
    const float  inv   = (float)(1.0 / (sqrt(var) + EPS));
    const float  fmean = (float)mean;

    const size_t idx = (size_t)blockIdx.x * NORM_THREADS + threadIdx.x;
    float4 v = x[idx];
    float4 o;
    o.x = (v.x != 0.0f) ? (v.x - fmean) * inv : 0.0f;
    o.y = (v.y != 0.0f) ? (v.y - fmean) * inv : 0.0f;
    o.z = (v.z != 0.0f) ? (v.z - fmean) * inv : 0.0f;
    o.w = (v.w != 0.0f) ? (v.w - fmean) * inv : 0.0f;
    out[idx] = o;
}

extern "C" void kernel_launch(void* const* d_in, const int* in_sizes, int n_in,
                              void* d_out, int out_size, void* d_ws, size_t ws_size,
                              hipStream_t stream) {
    const float4* x   = (const float4*)d_in[0];
    float4*       out = (float4*)d_out;
    double*       ws  = (double*)d_ws;

    // ws is poisoned 0xAA before every call -> zero the accumulators
    hipMemsetAsync(d_ws, 0, B * 3 * sizeof(double), stream);

    masked_stats_kernel<<<B * RED_BLOCKS_PS, RED_THREADS, 0, stream>>>(x, ws);
    masked_norm_kernel<<<B * NORM_BLOCKS_PS, NORM_THREADS, 0, stream>>>(x, out, ws);
}

// Round 3
// 473.928 us; speedup vs baseline: 1.0428x; 1.0428x over previous
//
#include <hip/hip_runtime.h>

// MaskedNormalize: x (16, 4, 1024, 1024) fp32. valid = x != 0.
// out = valid ? (x - mean) / (sqrt(var) + eps) : 0, per-sample masked stats.
// Masked-out entries are exactly 0 -> contribute nothing to S1/S2; m2 == 0 analytically.
//
// 3 dispatches: stats (per-block partials, fp32 chains, no atomics) ->
// mid (reduce partials -> per-sample {mean, inv} floats) -> norm (4 float4/thread,
// nontemporal stores to keep x resident in the 256 MiB L3 for its own reads).

#define EPS 1e-5

typedef float v4f __attribute__((ext_vector_type(4)));   // native vec for nontemporal store

constexpr int B               = 16;
constexpr int VEC_PER_SAMPLE  = 1 << 20;   // float4 per sample (4 * 1024 * 1024 / 4)
constexpr int RED_BLOCKS_PS   = 128;
constexpr int RED_THREADS     = 256;
constexpr int RED_VPT         = VEC_PER_SAMPLE / (RED_BLOCKS_PS * RED_THREADS);  // 32
constexpr int NORM_THREADS    = 256;
constexpr int NORM_VPT        = 4;
constexpr int NORM_BLOCKS_PS  = VEC_PER_SAMPLE / (NORM_THREADS * NORM_VPT);      // 1024

// ws layout: [0, 2048*3) doubles = per-block partials (s1, s2, cnt); then float2 fin[16]
constexpr size_t FIN_OFFSET = (size_t)B * RED_BLOCKS_PS * 3 * sizeof(double);    // 49152

// Pass 1: per-block partial {sum, sumsq, count}. fp32 accumulation in 4 independent
// chains (<=128 elems/chain -> ~1e-5 rel error), double for cross-lane reduction.
__global__ __launch_bounds__(RED_THREADS)
void masked_stats_kernel(const float4* __restrict__ x, double* __restrict__ part) {
    const int sample = blockIdx.x / RED_BLOCKS_PS;
    const int blk    = blockIdx.x % RED_BLOCKS_PS;
    const float4* xs = x + (size_t)sample * VEC_PER_SAMPLE
                         + (size_t)blk * (RED_THREADS * RED_VPT);

    float s1[4] = {0.f, 0.f, 0.f, 0.f};
    float s2[4] = {0.f, 0.f, 0.f, 0.f};
    int   cn[4] = {0, 0, 0, 0};

    for (int k = 0; k < RED_VPT; k += 4) {
        #pragma unroll
        for (int u = 0; u < 4; ++u) {
            float4 v = xs[(k + u) * RED_THREADS + threadIdx.x];
            s1[u] += (v.x + v.y) + (v.z + v.w);
            s2[u] += v.x * v.x;
            s2[u] += v.y * v.y;
            s2[u] += v.z * v.z;
            s2[u] += v.w * v.w;
            cn[u] += (v.x != 0.0f) + (v.y != 0.0f) + (v.z != 0.0f) + (v.w != 0.0f);
        }
    }

    double d1 = ((double)s1[0] + s1[1]) + ((double)s1[2] + s1[3]);
    double d2 = ((double)s2[0] + s2[1]) + ((double)s2[2] + s2[3]);
    int    ct = (cn[0] + cn[1]) + (cn[2] + cn[3]);

    #pragma unroll
    for (int off = 32; off > 0; off >>= 1) {
        d1 += __shfl_down(d1, off);
        d2 += __shfl_down(d2, off);
        ct += __shfl_down(ct, off);
    }

    __shared__ double L1[4], L2[4];
    __shared__ int    LC[4];
    const int wave = threadIdx.x >> 6;
    if ((threadIdx.x & 63) == 0) { L1[wave] = d1; L2[wave] = d2; LC[wave] = ct; }
    __syncthreads();
    if (threadIdx.x == 0) {
        double t1 = 0.0, t2 = 0.0; int tc = 0;
        #pragma unroll
        for (int w = 0; w < 4; ++w) { t1 += L1[w]; t2 += L2[w]; tc += LC[w]; }
        part[(size_t)blockIdx.x * 3 + 0] = t1;
        part[(size_t)blockIdx.x * 3 + 1] = t2;
        part[(size_t)blockIdx.x * 3 + 2] = (double)tc;
    }
}

// Mid: one block per sample; 128 threads, one partial each. Writes {mean, inv} floats.
__global__ __launch_bounds__(128)
void finalize_stats_kernel(const double* __restrict__ part, float2* __restrict__ fin) {
    const int sample = blockIdx.x;
    const size_t p = ((size_t)sample * RED_BLOCKS_PS + threadIdx.x) * 3;
    double d1 = part[p + 0];
    double d2 = part[p + 1];
    double dc = part[p + 2];

    #pragma unroll
    for (int off = 32; off > 0; off >>= 1) {
        d1 += __shfl_down(d1, off);
        d2 += __shfl_down(d2, off);
        dc += __shfl_down(dc, off);
    }

    __shared__ double L1[2], L2[2], LC[2];
    const int wave = threadIdx.x >> 6;
    if ((threadIdx.x & 63) == 0) { L1[wave] = d1; L2[wave] = d2; LC[wave] = dc; }
    __syncthreads();
    if (threadIdx.x == 0) {
        double S1 = L1[0] + L1[1];
        double S2 = L2[0] + L2[1];
        double n  = LC[0] + LC[1];
        double mean = S1 / n;
        double var  = (S2 - S1 * S1 / n) / (n - 1.0);
        float2 mi;
        mi.x = (float)mean;
        mi.y = (float)(1.0 / (sqrt(var) + EPS));
        fin[sample] = mi;
    }
}

// Pass 2: out = valid ? (x - mean) * inv : 0. Nontemporal stores (out never re-read;
// keep x in L3).
__global__ __launch_bounds__(NORM_THREADS)
void masked_norm_kernel(const float4* __restrict__ x, v4f* __restrict__ out,
                        const float2* __restrict__ fin) {
    const int sample = blockIdx.x / NORM_BLOCKS_PS;
    const int blk    = blockIdx.x % NORM_BLOCKS_PS;
    const float2 mi  = fin[sample];     // wave-uniform -> scalar load
    const float mean = mi.x, inv = mi.y;

    const size_t base = (size_t)sample * VEC_PER_SAMPLE
                      + (size_t)blk * (NORM_THREADS * NORM_VPT);

    #pragma unroll
    for (int u = 0; u < NORM_VPT; ++u) {
        const size_t idx = base + (size_t)u * NORM_THREADS + threadIdx.x;
        float4 v = x[idx];
        v4f o;
        o.x = (v.x != 0.0f) ? (v.x - mean) * inv : 0.0f;
        o.y = (v.y != 0.0f) ? (v.y - mean) * inv : 0.0f;
        o.z = (v.z != 0.0f) ? (v.z - mean) * inv : 0.0f;
        o.w = (v.w != 0.0f) ? (v.w - mean) * inv : 0.0f;
        __builtin_nontemporal_store(o, &out[idx]);
    }
}

extern "C" void kernel_launch(void* const* d_in, const int* in_sizes, int n_in,
                              void* d_out, int out_size, void* d_ws, size_t ws_size,
                              hipStream_t stream) {
    const float4* x    = (const float4*)d_in[0];
    v4f*          out  = (v4f*)d_out;
    double*       part = (double*)d_ws;
    float2*       fin  = (float2*)((char*)d_ws + FIN_OFFSET);

    masked_stats_kernel<<<B * RED_BLOCKS_PS, RED_THREADS, 0, stream>>>(x, part);
    finalize_stats_kernel<<<B, 128, 0, stream>>>(part, fin);
    masked_norm_kernel<<<B * NORM_BLOCKS_PS, NORM_THREADS, 0, stream>>>(x, out, fin);
}